// Round 4
// baseline (621.336 us; speedup 1.0000x reference)
//
#include <hip/hip_runtime.h>

// B=4,H=8,N=2048,DV=64. BH=32.
// P_d = stable argsort of v[:,d] (per bh), Q_d = inverse perm (rank), vs_d = sorted col.
// out[r,d] = vs_d[ Q_{(d+1)%64}[r] ]
// attn[r,:] = one_hot( P_0[ Q_1[r] ] )
//
// ws: Q ushort[32*64*2048] (8MB) | vs float[32*64*2048] (16MB) | P0 ushort[32*2048]
// d_out scratch: outT (16MB) and vT (16MB) live inside the attn region; both are
// fully consumed (by out_transpose / rank) BEFORE attn_zero overwrites the region.
//
// attn is produced in two decoupled passes:
//   attn_zero : dependency-free 536MB nontemporal zero-stream (pure write BW)
//   attn_spike: 1 thread/row resolves P0[Q_1[r]] and writes the single 1.0f
//
// NOTE: __builtin_nontemporal_store needs a clang ext_vector_type pointer,
// NOT HIP's float4 struct (compile error on gfx950).

#define SORT_N 2048
#define NBH 32
#define NDV 64
#define SLOT(i)  ((i) + ((i) >> 3))   // u64 pad: breaks 64B-stride bank aliasing
#define HS(i)    ((i) + ((i) >> 5))   // u32 pad for the histogram array

typedef float f32x4 __attribute__((ext_vector_type(4)));

// ---------------- Kernel 0: v transpose (coalesced column loads) ------------
__global__ __launch_bounds__(256) void v_transpose_kernel(
    const float* __restrict__ v, float* __restrict__ vT) {
  __shared__ float tile[64][65];
  const int blk = blockIdx.x;        // bh*32 + rtile
  const int bh = blk >> 5;
  const int r0 = (blk & 31) << 6;
  const int tx = threadIdx.x & 63;
  const int ty = threadIdx.x >> 6;   // 0..3
  for (int i = ty; i < 64; i += 4)   // read v[bh][r0+i][tx] coalesced
    tile[i][tx] = v[((size_t)((bh << 11) + r0 + i) << 6) + tx];
  __syncthreads();
  for (int i = ty; i < 64; i += 4)   // write vT[bh][i][r0+tx] coalesced
    vT[((size_t)((bh << 6) + i) << 11) + r0 + tx] = tile[tx][i];
}

// ---------------- Kernel 1: exact bucket-rank per column --------------------
// One WG per (bh,d) column. Thread t owns original indices {t+256e, e=0..7}.
__global__ __launch_bounds__(256) void rank_kernel(
    const float* __restrict__ vT, unsigned short* __restrict__ Q,
    float* __restrict__ vs, unsigned short* __restrict__ P0) {
  const int col = blockIdx.x;        // bh*64 + d
  const int bh  = col >> 6;
  const int d   = col & 63;
  const float* vcol = vT + ((size_t)col << 11);

  __shared__ unsigned base[2112];                       // HS-padded 2048 bins
  __shared__ unsigned long long bkt[SORT_N + 256];      // SLOT-padded scatter
  __shared__ float vsorted[SORT_N];
  __shared__ unsigned wsum[4];

  const int t = threadIdx.x;

  float x[8]; unsigned key[8]; int bk[8];
#pragma unroll
  for (int e = 0; e < 8; ++e) {
    float f = vcol[t + (e << 8)];                       // coalesced
    x[e] = f;
    unsigned u = __float_as_uint(f);
    key[e] = (u & 0x80000000u) ? ~u : (u | 0x80000000u);  // order-preserving bias
    // monotone bucket map: range [-2.75, 2.75] -> [0, 2048)
    float tb = fmaf(f, 372.3636f, 1024.0f);
    tb = fminf(fmaxf(tb, 0.0f), 2047.0f);
    bk[e] = (int)tb;                                    // trunc == floor (tb >= 0)
  }

  // zero histogram (incl. pad slots)
  for (int i = t; i < 2112; i += 256) base[i] = 0;
  __syncthreads();
#pragma unroll
  for (int e = 0; e < 8; ++e) atomicAdd(&base[HS(bk[e])], 1u);
  __syncthreads();

  // block exclusive scan over the 2048 bins (thread t owns bins 8t..8t+7)
  unsigned c[8];
#pragma unroll
  for (int e = 0; e < 8; ++e) c[e] = base[HS((t << 3) + e)];
  unsigned s = 0;
#pragma unroll
  for (int e = 0; e < 8; ++e) s += c[e];
  unsigned incl = s;
  for (int off = 1; off < 64; off <<= 1) {
    unsigned tmp = __shfl_up(incl, off);
    if ((t & 63) >= off) incl += tmp;
  }
  const int w = t >> 6;
  if ((t & 63) == 63) wsum[w] = incl;
  __syncthreads();
  unsigned run = incl - s;                              // exclusive within wave
  for (int i = 0; i < w; ++i) run += wsum[i];           // + earlier waves
#pragma unroll
  for (int e = 0; e < 8; ++e) {                         // own slots only: no race
    unsigned cc = c[e];
    base[HS((t << 3) + e)] = run;                       // exclusive bucket base
    run += cc;
  }
  __syncthreads();

  // scatter (key<<32|idx) into bucketed order (arbitrary order within bucket)
#pragma unroll
  for (int e = 0; e < 8; ++e) {
    unsigned idx = (unsigned)(t + (e << 8));
    unsigned long long me = ((unsigned long long)key[e] << 32) | idx;
    unsigned pos = atomicAdd(&base[HS(bk[e])], 1u);     // base[b] becomes bucket end
    bkt[SLOT(pos)] = me;
  }
  __syncthreads();

  // exact rank = bucket start + #{strictly smaller (key,idx) in bucket}
  unsigned short* Qcol = Q + ((size_t)col << 11);
  float* vscol = vs + ((size_t)col << 11);
#pragma unroll
  for (int e = 0; e < 8; ++e) {
    unsigned idx = (unsigned)(t + (e << 8));
    const int b = bk[e];
    unsigned end   = base[HS(b)];                       // post-scatter = bucket end
    unsigned start = (b == 0) ? 0u : base[HS(b - 1)];   // end of prev = my start
    unsigned long long me = ((unsigned long long)key[e] << 32) | idx;
    unsigned r = start;
    for (unsigned p = start; p < end; ++p)
      r += (bkt[SLOT(p)] < me) ? 1u : 0u;
    Qcol[idx] = (unsigned short)r;                      // coalesced ushort write
    vsorted[r] = x[e];                                  // LDS scatter
    if (d == 0) P0[((size_t)bh << 11) + r] = (unsigned short)idx;
  }
  __syncthreads();
#pragma unroll
  for (int e = 0; e < 8; ++e) {                         // coalesced vs write
    int rr = t + (e << 8);
    vscol[rr] = vsorted[rr];
  }
}

// ------- Kernel 2a: outT[(bh,d)][r] = vs_d[Q_{d+1}[r]]  (all coalesced) -----
__global__ __launch_bounds__(256) void out_colT_kernel(
    const unsigned short* __restrict__ Q, const float* __restrict__ vs,
    float* __restrict__ outT) {
  const int b  = blockIdx.x;         // bh*64 + d
  const int bh = b >> 6;
  const int d  = b & 63;
  const int dn = (d + 1) & 63;
  const int t  = threadIdx.x;

  __shared__ float col[SORT_N];      // 8 KiB
  const float4* vcol4 = (const float4*)(vs + ((size_t)b << 11));
  float4* col4 = (float4*)col;
  for (int r4 = t; r4 < 512; r4 += 256) col4[r4] = vcol4[r4];   // 16B coalesced
  __syncthreads();

  const ushort4* Qv = (const ushort4*)(Q + ((size_t)((bh << 6) + dn) << 11));
  float4* ov = (float4*)(outT + ((size_t)b << 11));
  for (int r4 = t; r4 < 512; r4 += 256) {
    ushort4 qq = Qv[r4];             // 8B coalesced ushort read
    float4 val;
    val.x = col[qq.x]; val.y = col[qq.y];
    val.z = col[qq.z]; val.w = col[qq.w];
    ov[r4] = val;                    // 16B coalesced write
  }
}

// ------- Kernel 2b: out[r][d] = outT[d][r]  (64x64 LDS tile transpose) ------
__global__ __launch_bounds__(256) void out_transpose_kernel(
    const float* __restrict__ outT, float* __restrict__ out) {
  __shared__ float tile[64][65];     // +1 pad breaks bank conflicts
  const int blk = blockIdx.x;        // bh*32 + rtile
  const int bh = blk >> 5;
  const int r0 = (blk & 31) << 6;    // 64-row tile
  const int tx = threadIdx.x & 63;
  const int ty = threadIdx.x >> 6;   // 0..3

  for (int i = ty; i < 64; i += 4)   // read outT[d=i][r0+tx] coalesced
    tile[i][tx] = outT[(((size_t)(bh << 6) + i) << 11) + r0 + tx];
  __syncthreads();
  for (int i = ty; i < 64; i += 4)   // write out[r0+i][d=tx] coalesced
    out[(((size_t)(bh << 11) + r0 + i) << 6) + tx] = tile[tx][i];
}

// ---------- Kernel 3a: attn zero-stream (no deps, pure write BW) ------------
__global__ __launch_bounds__(256) void attn_zero_kernel(
    f32x4* __restrict__ attn4, int n4) {
  int i = blockIdx.x * 256 + threadIdx.x;
  const int stride = gridDim.x * 256;
  const f32x4 z = {0.0f, 0.0f, 0.0f, 0.0f};
  for (; i < n4; i += stride)
    __builtin_nontemporal_store(z, &attn4[i]);
}

// ---------- Kernel 3b: attn spikes (1 thread per row) -----------------------
__global__ __launch_bounds__(256) void attn_spike_kernel(
    const unsigned short* __restrict__ P0, const unsigned short* __restrict__ Q,
    float* __restrict__ attn) {
  int row = blockIdx.x * 256 + threadIdx.x;   // bh*2048 + r, 0..65535
  int bh = row >> 11;
  int r  = row & 2047;
  int q   = Q[(((bh << 6) + 1) << 11) + r];   // Q_1[r]  (coalesced over r)
  int idx = P0[(bh << 11) + q];               // P_0[Q_1[r]] (L2 gather)
  attn[((size_t)row << 11) + idx] = 1.0f;     // single scattered 4B write
}

extern "C" void kernel_launch(void* const* d_in, const int* in_sizes, int n_in,
                              void* d_out, int out_size, void* d_ws, size_t ws_size,
                              hipStream_t stream) {
  const float* v = (const float*)d_in[2];     // q,k unused by reference
  float* out  = (float*)d_out;
  float* attn = out + (size_t)NBH * SORT_N * NDV;
  // scratch inside the attn region (536MB); both consumed before attn_zero:
  float* outT = attn;                                   // 16MB
  float* vT   = attn + (size_t)NBH * SORT_N * NDV;      // next 16MB

  unsigned short* Q  = (unsigned short*)d_ws;                             // 8 MiB
  float* vs          = (float*)((char*)d_ws + (size_t)8 * 1024 * 1024);   // 16 MiB
  unsigned short* P0 = (unsigned short*)((char*)d_ws + (size_t)24 * 1024 * 1024);

  const int n4 = NBH * SORT_N * (SORT_N / 4);           // 33.5M float4s

  v_transpose_kernel<<<NBH * 32, 256, 0, stream>>>(v, vT);
  rank_kernel<<<NBH * NDV, 256, 0, stream>>>(vT, Q, vs, P0);
  out_colT_kernel<<<NBH * NDV, 256, 0, stream>>>(Q, vs, outT);
  out_transpose_kernel<<<NBH * 32, 256, 0, stream>>>(outT, out);
  attn_zero_kernel<<<8192, 256, 0, stream>>>((f32x4*)attn, n4);
  attn_spike_kernel<<<NBH * SORT_N / 256, 256, 0, stream>>>(P0, Q, attn);
}

// Round 5
// 609.365 us; speedup vs baseline: 1.0196x; 1.0196x over previous
//
#include <hip/hip_runtime.h>

// B=4,H=8,N=2048,DV=64. BH=32.
// P_d = stable argsort of v[:,d] (per bh), Q_d = inverse perm (rank), vs_d = sorted col.
// out[r,d] = vs_d[ Q_{(d+1)%64}[r] ]
// attn[r,:] = one_hot( P_0[ Q_1[r] ] )
//
// ws: Q ushort[32*64*2048] (8MB) | vs float[32*64*2048] (16MB) |
//     P0 ushort[32*2048] (128KB) | spike uint[32*2048] (256KB)
// d_out scratch: outT (16MB) and vT (16MB) live inside the attn region; both are
// fully consumed (by out_transpose / rank) BEFORE the attn kernel overwrites it.
//
// R4 post-mortem: splitting attn into zero+spike cost +32us (fused one-hot was
// already ~write-floor; 65536 resident blocks hide the idx-chain latency).
// Reverted to FUSED one-hot; spike index precomputed for free inside the
// d==0 out_colT block (it already reads Q_1), so attn needs 1 uniform load/row.

#define SORT_N 2048
#define NBH 32
#define NDV 64
#define SLOT(i)  ((i) + ((i) >> 3))   // u64 pad: breaks 64B-stride bank aliasing
#define HS(i)    ((i) + ((i) >> 5))   // u32 pad for the histogram array

typedef float f32x4 __attribute__((ext_vector_type(4)));

// ---------------- Kernel 0: v transpose (coalesced column loads) ------------
__global__ __launch_bounds__(256) void v_transpose_kernel(
    const float* __restrict__ v, float* __restrict__ vT) {
  __shared__ float tile[64][65];
  const int blk = blockIdx.x;        // bh*32 + rtile
  const int bh = blk >> 5;
  const int r0 = (blk & 31) << 6;
  const int tx = threadIdx.x & 63;
  const int ty = threadIdx.x >> 6;   // 0..3
  for (int i = ty; i < 64; i += 4)   // read v[bh][r0+i][tx] coalesced
    tile[i][tx] = v[((size_t)((bh << 11) + r0 + i) << 6) + tx];
  __syncthreads();
  for (int i = ty; i < 64; i += 4)   // write vT[bh][i][r0+tx] coalesced
    vT[((size_t)((bh << 6) + i) << 11) + r0 + tx] = tile[tx][i];
}

// ---------------- Kernel 1: exact bucket-rank per column --------------------
// One WG per (bh,d) column. Thread t owns original indices {t+256e, e=0..7}.
__global__ __launch_bounds__(256) void rank_kernel(
    const float* __restrict__ vT, unsigned short* __restrict__ Q,
    float* __restrict__ vs, unsigned short* __restrict__ P0) {
  const int col = blockIdx.x;        // bh*64 + d
  const int bh  = col >> 6;
  const int d   = col & 63;
  const float* vcol = vT + ((size_t)col << 11);

  __shared__ unsigned base[2112];                       // HS-padded 2048 bins
  __shared__ unsigned long long bkt[SORT_N + 256];      // SLOT-padded scatter
  __shared__ float vsorted[SORT_N];
  __shared__ unsigned wsum[4];

  const int t = threadIdx.x;

  float x[8]; unsigned key[8]; int bk[8];
#pragma unroll
  for (int e = 0; e < 8; ++e) {
    float f = vcol[t + (e << 8)];                       // coalesced
    x[e] = f;
    unsigned u = __float_as_uint(f);
    key[e] = (u & 0x80000000u) ? ~u : (u | 0x80000000u);  // order-preserving bias
    // monotone bucket map: range [-2.75, 2.75] -> [0, 2048)
    float tb = fmaf(f, 372.3636f, 1024.0f);
    tb = fminf(fmaxf(tb, 0.0f), 2047.0f);
    bk[e] = (int)tb;                                    // trunc == floor (tb >= 0)
  }

  // zero histogram (incl. pad slots)
  for (int i = t; i < 2112; i += 256) base[i] = 0;
  __syncthreads();
#pragma unroll
  for (int e = 0; e < 8; ++e) atomicAdd(&base[HS(bk[e])], 1u);
  __syncthreads();

  // block exclusive scan over the 2048 bins (thread t owns bins 8t..8t+7)
  unsigned c[8];
#pragma unroll
  for (int e = 0; e < 8; ++e) c[e] = base[HS((t << 3) + e)];
  unsigned s = 0;
#pragma unroll
  for (int e = 0; e < 8; ++e) s += c[e];
  unsigned incl = s;
  for (int off = 1; off < 64; off <<= 1) {
    unsigned tmp = __shfl_up(incl, off);
    if ((t & 63) >= off) incl += tmp;
  }
  const int w = t >> 6;
  if ((t & 63) == 63) wsum[w] = incl;
  __syncthreads();
  unsigned run = incl - s;                              // exclusive within wave
  for (int i = 0; i < w; ++i) run += wsum[i];           // + earlier waves
#pragma unroll
  for (int e = 0; e < 8; ++e) {                         // own slots only: no race
    unsigned cc = c[e];
    base[HS((t << 3) + e)] = run;                       // exclusive bucket base
    run += cc;
  }
  __syncthreads();

  // scatter (key<<32|idx) into bucketed order (arbitrary order within bucket)
#pragma unroll
  for (int e = 0; e < 8; ++e) {
    unsigned idx = (unsigned)(t + (e << 8));
    unsigned long long me = ((unsigned long long)key[e] << 32) | idx;
    unsigned pos = atomicAdd(&base[HS(bk[e])], 1u);     // base[b] becomes bucket end
    bkt[SLOT(pos)] = me;
  }
  __syncthreads();

  // exact rank = bucket start + #{strictly smaller (key,idx) in bucket}
  unsigned short* Qcol = Q + ((size_t)col << 11);
  float* vscol = vs + ((size_t)col << 11);
#pragma unroll
  for (int e = 0; e < 8; ++e) {
    unsigned idx = (unsigned)(t + (e << 8));
    const int b = bk[e];
    unsigned end   = base[HS(b)];                       // post-scatter = bucket end
    unsigned start = (b == 0) ? 0u : base[HS(b - 1)];   // end of prev = my start
    unsigned long long me = ((unsigned long long)key[e] << 32) | idx;
    unsigned r = start;
    for (unsigned p = start; p < end; ++p)
      r += (bkt[SLOT(p)] < me) ? 1u : 0u;
    Qcol[idx] = (unsigned short)r;                      // coalesced ushort write
    vsorted[r] = x[e];                                  // LDS scatter
    if (d == 0) P0[((size_t)bh << 11) + r] = (unsigned short)idx;
  }
  __syncthreads();
#pragma unroll
  for (int e = 0; e < 8; ++e) {                         // coalesced vs write
    int rr = t + (e << 8);
    vscol[rr] = vsorted[rr];
  }
}

// ------- Kernel 2a: outT[(bh,d)][r] = vs_d[Q_{d+1}[r]]  (all coalesced) -----
// d==0 blocks additionally emit spike[bh*2048+r] = P0[Q_1[r]] (they hold Q_1).
__global__ __launch_bounds__(256) void out_colT_kernel(
    const unsigned short* __restrict__ Q, const float* __restrict__ vs,
    const unsigned short* __restrict__ P0, float* __restrict__ outT,
    unsigned* __restrict__ spike) {
  const int b  = blockIdx.x;         // bh*64 + d
  const int bh = b >> 6;
  const int d  = b & 63;
  const int dn = (d + 1) & 63;
  const int t  = threadIdx.x;

  __shared__ float col[SORT_N];      // 8 KiB
  __shared__ unsigned short P0s[SORT_N];  // 4 KiB (used only by d==0 blocks)
  const float4* vcol4 = (const float4*)(vs + ((size_t)b << 11));
  float4* col4 = (float4*)col;
  for (int r4 = t; r4 < 512; r4 += 256) col4[r4] = vcol4[r4];   // 16B coalesced
  if (d == 0)
    for (int r = t; r < SORT_N; r += 256) P0s[r] = P0[((size_t)bh << 11) + r];
  __syncthreads();

  const ushort4* Qv = (const ushort4*)(Q + ((size_t)((bh << 6) + dn) << 11));
  float4* ov = (float4*)(outT + ((size_t)b << 11));
  for (int r4 = t; r4 < 512; r4 += 256) {
    ushort4 qq = Qv[r4];             // 8B coalesced ushort read
    float4 val;
    val.x = col[qq.x]; val.y = col[qq.y];
    val.z = col[qq.z]; val.w = col[qq.w];
    ov[r4] = val;                    // 16B coalesced write
    if (d == 0) {                    // spike side-product: P0[Q_1[r]]
      int r = r4 << 2;
      unsigned base_i = ((unsigned)bh << 11) + (unsigned)r;
      spike[base_i + 0] = P0s[qq.x];
      spike[base_i + 1] = P0s[qq.y];
      spike[base_i + 2] = P0s[qq.z];
      spike[base_i + 3] = P0s[qq.w];
    }
  }
}

// ------- Kernel 2b: out[r][d] = outT[d][r]  (64x64 LDS tile transpose) ------
__global__ __launch_bounds__(256) void out_transpose_kernel(
    const float* __restrict__ outT, float* __restrict__ out) {
  __shared__ float tile[64][65];     // +1 pad breaks bank conflicts
  const int blk = blockIdx.x;        // bh*32 + rtile
  const int bh = blk >> 5;
  const int r0 = (blk & 31) << 6;    // 64-row tile
  const int tx = threadIdx.x & 63;
  const int ty = threadIdx.x >> 6;   // 0..3

  for (int i = ty; i < 64; i += 4)   // read outT[d=i][r0+tx] coalesced
    tile[i][tx] = outT[(((size_t)(bh << 6) + i) << 11) + r0 + tx];
  __syncthreads();
  for (int i = ty; i < 64; i += 4)   // write out[r0+i][d=tx] coalesced
    out[(((size_t)(bh << 11) + r0 + i) << 6) + tx] = tile[tx][i];
}

// ---------------- Kernel 3: fused attn one-hot (8 rows per block) -----------
__global__ __launch_bounds__(256) void attn_kernel(
    const unsigned* __restrict__ spike, f32x4* __restrict__ attn4) {
  const int t = threadIdx.x;
  int row = blockIdx.x << 3;         // 8 rows per block
#pragma unroll
  for (int rr = 0; rr < 8; ++rr, ++row) {
    const int idx = (int)spike[row]; // uniform scalar load (L2-resident 256KB)
    f32x4* rowp = attn4 + ((size_t)row << 9);   // 512 float4 per row
#pragma unroll
    for (int it = 0; it < 2; ++it) {
      int f4 = t + (it << 8);
      int basei = f4 << 2;
      f32x4 val;
      val.x = (basei + 0 == idx) ? 1.0f : 0.0f;
      val.y = (basei + 1 == idx) ? 1.0f : 0.0f;
      val.z = (basei + 2 == idx) ? 1.0f : 0.0f;
      val.w = (basei + 3 == idx) ? 1.0f : 0.0f;
      __builtin_nontemporal_store(val, &rowp[f4]);
    }
  }
}

extern "C" void kernel_launch(void* const* d_in, const int* in_sizes, int n_in,
                              void* d_out, int out_size, void* d_ws, size_t ws_size,
                              hipStream_t stream) {
  const float* v = (const float*)d_in[2];     // q,k unused by reference
  float* out  = (float*)d_out;
  float* attn = out + (size_t)NBH * SORT_N * NDV;
  // scratch inside the attn region (536MB); both consumed before attn_kernel:
  float* outT = attn;                                   // 16MB
  float* vT   = attn + (size_t)NBH * SORT_N * NDV;      // next 16MB

  unsigned short* Q  = (unsigned short*)d_ws;                             // 8 MiB
  float* vs          = (float*)((char*)d_ws + (size_t)8 * 1024 * 1024);   // 16 MiB
  unsigned short* P0 = (unsigned short*)((char*)d_ws + (size_t)24 * 1024 * 1024);
  unsigned* spike    = (unsigned*)((char*)d_ws + (size_t)24 * 1024 * 1024 + 256 * 1024);

  v_transpose_kernel<<<NBH * 32, 256, 0, stream>>>(v, vT);
  rank_kernel<<<NBH * NDV, 256, 0, stream>>>(vT, Q, vs, P0);
  out_colT_kernel<<<NBH * NDV, 256, 0, stream>>>(Q, vs, P0, outT, spike);
  out_transpose_kernel<<<NBH * 32, 256, 0, stream>>>(outT, out);
  attn_kernel<<<NBH * SORT_N / 8, 256, 0, stream>>>(spike, (f32x4*)attn);
}

// Round 6
// 598.841 us; speedup vs baseline: 1.0376x; 1.0176x over previous
//
#include <hip/hip_runtime.h>

// B=4,H=8,N=2048,DV=64. BH=32.
// P_d = stable argsort of v[:,d] (per bh), Q_d = inverse perm (rank), vs_d = sorted col.
// out[r,d] = vs_d[ Q_{(d+1)%64}[r] ]
// attn[r,:] = one_hot( P_0[ Q_1[r] ] )
//
// ws: Q ushort[32*64*2048] (8MB) | vs float[32*64*2048] (16MB) |
//     P0 ushort[32*2048] (128KB) | spike uint[32*2048] (256KB)
// d_out scratch: outT (16MB) and vT (16MB) live inside the attn region; both are
// fully consumed (by out_transpose / rank) BEFORE the memset wipes the region.
//
// Attn lessons (R4/R5 measured): __builtin_nontemporal_store costs ~2x on this
// write stream (R4 +32us, R5 +20us vs plain R1) -- NT is banned. Plain-store
// fused one-hot runs ~3.1 TB/s vs fillBufferAligned's 6.27 TB/s on the same
// buffer, so attn zeroing is delegated to hipMemsetAsync (the rocclr fill
// kernel), followed by a tiny spike-write kernel using spike[] precomputed
// for free in the d==0 out_colT block.

#define SORT_N 2048
#define NBH 32
#define NDV 64
#define SLOT(i)  ((i) + ((i) >> 3))   // u64 pad: breaks 64B-stride bank aliasing
#define HS(i)    ((i) + ((i) >> 5))   // u32 pad for the histogram array

// ---------------- Kernel 0: v transpose (coalesced column loads) ------------
__global__ __launch_bounds__(256) void v_transpose_kernel(
    const float* __restrict__ v, float* __restrict__ vT) {
  __shared__ float tile[64][65];
  const int blk = blockIdx.x;        // bh*32 + rtile
  const int bh = blk >> 5;
  const int r0 = (blk & 31) << 6;
  const int tx = threadIdx.x & 63;
  const int ty = threadIdx.x >> 6;   // 0..3
  for (int i = ty; i < 64; i += 4)   // read v[bh][r0+i][tx] coalesced
    tile[i][tx] = v[((size_t)((bh << 11) + r0 + i) << 6) + tx];
  __syncthreads();
  for (int i = ty; i < 64; i += 4)   // write vT[bh][i][r0+tx] coalesced
    vT[((size_t)((bh << 6) + i) << 11) + r0 + tx] = tile[tx][i];
}

// ---------------- Kernel 1: exact bucket-rank per column --------------------
// One WG per (bh,d) column. Thread t owns original indices {t+256e, e=0..7}.
__global__ __launch_bounds__(256) void rank_kernel(
    const float* __restrict__ vT, unsigned short* __restrict__ Q,
    float* __restrict__ vs, unsigned short* __restrict__ P0) {
  const int col = blockIdx.x;        // bh*64 + d
  const int bh  = col >> 6;
  const int d   = col & 63;
  const float* vcol = vT + ((size_t)col << 11);

  __shared__ unsigned base[2112];                       // HS-padded 2048 bins
  __shared__ unsigned long long bkt[SORT_N + 256];      // SLOT-padded scatter
  __shared__ float vsorted[SORT_N];
  __shared__ unsigned wsum[4];

  const int t = threadIdx.x;

  float x[8]; unsigned key[8]; int bk[8];
#pragma unroll
  for (int e = 0; e < 8; ++e) {
    float f = vcol[t + (e << 8)];                       // coalesced
    x[e] = f;
    unsigned u = __float_as_uint(f);
    key[e] = (u & 0x80000000u) ? ~u : (u | 0x80000000u);  // order-preserving bias
    // monotone bucket map: range [-2.75, 2.75] -> [0, 2048)
    float tb = fmaf(f, 372.3636f, 1024.0f);
    tb = fminf(fmaxf(tb, 0.0f), 2047.0f);
    bk[e] = (int)tb;                                    // trunc == floor (tb >= 0)
  }

  // zero histogram (incl. pad slots)
  for (int i = t; i < 2112; i += 256) base[i] = 0;
  __syncthreads();
#pragma unroll
  for (int e = 0; e < 8; ++e) atomicAdd(&base[HS(bk[e])], 1u);
  __syncthreads();

  // block exclusive scan over the 2048 bins (thread t owns bins 8t..8t+7)
  unsigned c[8];
#pragma unroll
  for (int e = 0; e < 8; ++e) c[e] = base[HS((t << 3) + e)];
  unsigned s = 0;
#pragma unroll
  for (int e = 0; e < 8; ++e) s += c[e];
  unsigned incl = s;
  for (int off = 1; off < 64; off <<= 1) {
    unsigned tmp = __shfl_up(incl, off);
    if ((t & 63) >= off) incl += tmp;
  }
  const int w = t >> 6;
  if ((t & 63) == 63) wsum[w] = incl;
  __syncthreads();
  unsigned run = incl - s;                              // exclusive within wave
  for (int i = 0; i < w; ++i) run += wsum[i];           // + earlier waves
#pragma unroll
  for (int e = 0; e < 8; ++e) {                         // own slots only: no race
    unsigned cc = c[e];
    base[HS((t << 3) + e)] = run;                       // exclusive bucket base
    run += cc;
  }
  __syncthreads();

  // scatter (key<<32|idx) into bucketed order (arbitrary order within bucket)
#pragma unroll
  for (int e = 0; e < 8; ++e) {
    unsigned idx = (unsigned)(t + (e << 8));
    unsigned long long me = ((unsigned long long)key[e] << 32) | idx;
    unsigned pos = atomicAdd(&base[HS(bk[e])], 1u);     // base[b] becomes bucket end
    bkt[SLOT(pos)] = me;
  }
  __syncthreads();

  // exact rank = bucket start + #{strictly smaller (key,idx) in bucket}
  unsigned short* Qcol = Q + ((size_t)col << 11);
  float* vscol = vs + ((size_t)col << 11);
#pragma unroll
  for (int e = 0; e < 8; ++e) {
    unsigned idx = (unsigned)(t + (e << 8));
    const int b = bk[e];
    unsigned end   = base[HS(b)];                       // post-scatter = bucket end
    unsigned start = (b == 0) ? 0u : base[HS(b - 1)];   // end of prev = my start
    unsigned long long me = ((unsigned long long)key[e] << 32) | idx;
    unsigned r = start;
    for (unsigned p = start; p < end; ++p)
      r += (bkt[SLOT(p)] < me) ? 1u : 0u;
    Qcol[idx] = (unsigned short)r;                      // coalesced ushort write
    vsorted[r] = x[e];                                  // LDS scatter
    if (d == 0) P0[((size_t)bh << 11) + r] = (unsigned short)idx;
  }
  __syncthreads();
#pragma unroll
  for (int e = 0; e < 8; ++e) {                         // coalesced vs write
    int rr = t + (e << 8);
    vscol[rr] = vsorted[rr];
  }
}

// ------- Kernel 2a: outT[(bh,d)][r] = vs_d[Q_{d+1}[r]]  (all coalesced) -----
// d==0 blocks additionally emit spike[bh*2048+r] = P0[Q_1[r]] (they hold Q_1).
__global__ __launch_bounds__(256) void out_colT_kernel(
    const unsigned short* __restrict__ Q, const float* __restrict__ vs,
    const unsigned short* __restrict__ P0, float* __restrict__ outT,
    unsigned* __restrict__ spike) {
  const int b  = blockIdx.x;         // bh*64 + d
  const int bh = b >> 6;
  const int d  = b & 63;
  const int dn = (d + 1) & 63;
  const int t  = threadIdx.x;

  __shared__ float col[SORT_N];      // 8 KiB
  __shared__ unsigned short P0s[SORT_N];  // 4 KiB (used only by d==0 blocks)
  const float4* vcol4 = (const float4*)(vs + ((size_t)b << 11));
  float4* col4 = (float4*)col;
  for (int r4 = t; r4 < 512; r4 += 256) col4[r4] = vcol4[r4];   // 16B coalesced
  if (d == 0)
    for (int r = t; r < SORT_N; r += 256) P0s[r] = P0[((size_t)bh << 11) + r];
  __syncthreads();

  const ushort4* Qv = (const ushort4*)(Q + ((size_t)((bh << 6) + dn) << 11));
  float4* ov = (float4*)(outT + ((size_t)b << 11));
  for (int r4 = t; r4 < 512; r4 += 256) {
    ushort4 qq = Qv[r4];             // 8B coalesced ushort read
    float4 val;
    val.x = col[qq.x]; val.y = col[qq.y];
    val.z = col[qq.z]; val.w = col[qq.w];
    ov[r4] = val;                    // 16B coalesced write
    if (d == 0) {                    // spike side-product: P0[Q_1[r]]
      int r = r4 << 2;
      unsigned base_i = ((unsigned)bh << 11) + (unsigned)r;
      spike[base_i + 0] = P0s[qq.x];
      spike[base_i + 1] = P0s[qq.y];
      spike[base_i + 2] = P0s[qq.z];
      spike[base_i + 3] = P0s[qq.w];
    }
  }
}

// ------- Kernel 2b: out[r][d] = outT[d][r]  (64x64 LDS tile transpose) ------
__global__ __launch_bounds__(256) void out_transpose_kernel(
    const float* __restrict__ outT, float* __restrict__ out) {
  __shared__ float tile[64][65];     // +1 pad breaks bank conflicts
  const int blk = blockIdx.x;        // bh*32 + rtile
  const int bh = blk >> 5;
  const int r0 = (blk & 31) << 6;    // 64-row tile
  const int tx = threadIdx.x & 63;
  const int ty = threadIdx.x >> 6;   // 0..3

  for (int i = ty; i < 64; i += 4)   // read outT[d=i][r0+tx] coalesced
    tile[i][tx] = outT[(((size_t)(bh << 6) + i) << 11) + r0 + tx];
  __syncthreads();
  for (int i = ty; i < 64; i += 4)   // write out[r0+i][d=tx] coalesced
    out[(((size_t)(bh << 11) + r0 + i) << 6) + tx] = tile[tx][i];
}

// ---------- Kernel 3: attn spikes (attn pre-zeroed by hipMemsetAsync) -------
__global__ __launch_bounds__(256) void attn_spike_kernel(
    const unsigned* __restrict__ spike, float* __restrict__ attn) {
  int row = blockIdx.x * 256 + threadIdx.x;   // 0..65535
  int idx = (int)spike[row];                  // coalesced 4B read
  attn[((size_t)row << 11) + idx] = 1.0f;     // single scattered 4B write
}

extern "C" void kernel_launch(void* const* d_in, const int* in_sizes, int n_in,
                              void* d_out, int out_size, void* d_ws, size_t ws_size,
                              hipStream_t stream) {
  const float* v = (const float*)d_in[2];     // q,k unused by reference
  float* out  = (float*)d_out;
  float* attn = out + (size_t)NBH * SORT_N * NDV;
  // scratch inside the attn region (536MB); both consumed before the memset:
  float* outT = attn;                                   // 16MB
  float* vT   = attn + (size_t)NBH * SORT_N * NDV;      // next 16MB

  unsigned short* Q  = (unsigned short*)d_ws;                             // 8 MiB
  float* vs          = (float*)((char*)d_ws + (size_t)8 * 1024 * 1024);   // 16 MiB
  unsigned short* P0 = (unsigned short*)((char*)d_ws + (size_t)24 * 1024 * 1024);
  unsigned* spike    = (unsigned*)((char*)d_ws + (size_t)24 * 1024 * 1024 + 256 * 1024);

  const size_t attn_bytes = (size_t)NBH * SORT_N * SORT_N * sizeof(float);  // 536.9MB

  v_transpose_kernel<<<NBH * 32, 256, 0, stream>>>(v, vT);
  rank_kernel<<<NBH * NDV, 256, 0, stream>>>(vT, Q, vs, P0);
  out_colT_kernel<<<NBH * NDV, 256, 0, stream>>>(Q, vs, P0, outT, spike);
  out_transpose_kernel<<<NBH * 32, 256, 0, stream>>>(outT, out);
  hipMemsetAsync(attn, 0, attn_bytes, stream);          // rocclr fill: ~6.27 TB/s
  attn_spike_kernel<<<NBH * SORT_N / 256, 256, 0, stream>>>(spike, attn);
}

// Round 8
// 590.640 us; speedup vs baseline: 1.0520x; 1.0139x over previous
//
#include <hip/hip_runtime.h>

// B=4,H=8,N=2048,DV=64. BH=32.
// P_d = stable argsort of v[:,d] (per bh), Q_d = inverse perm (rank), vs_d = sorted col.
// out[r,d] = vs_d[ Q_{(d+1)%64}[r] ]
// attn[r,:] = one_hot( P_0[ Q_1[r] ] )
//
// ws: Q ushort[32*64*2048] (8MB) | vs float[32*64*2048] (16MB) |
//     P0 ushort[32*2048] (128KB) | spike uint[32*2048] (256KB)
// d_out scratch: outT (16MB) and vT (16MB) live inside the attn region; both are
// fully consumed (by out_transpose / rank) BEFORE attn_kernel overwrites it.
//
// Measured lessons (R4/R5/R6):
//  - __builtin_nontemporal_store costs ~1.4x on the 536MB attn stream. BANNED.
//  - hipMemsetAsync zero + spike == fused one-hot + 9us. The fused plain-store
//    one-hot ALREADY runs at fill speed (~6.2 TB/s). Attn has no headroom.
//  - 1 row/block, 256 threads, 2x float4/thread is the proven-best attn shape.

#define SORT_N 2048
#define NBH 32
#define NDV 64
#define SLOT(i)  ((i) + ((i) >> 3))   // u64 pad: breaks 64B-stride bank aliasing
#define HS(i)    ((i) + ((i) >> 5))   // u32 pad for the histogram array

// ---------------- Kernel 0: v transpose (coalesced column loads) ------------
__global__ __launch_bounds__(256) void v_transpose_kernel(
    const float* __restrict__ v, float* __restrict__ vT) {
  __shared__ float tile[64][65];
  const int blk = blockIdx.x;        // bh*32 + rtile
  const int bh = blk >> 5;
  const int r0 = (blk & 31) << 6;
  const int tx = threadIdx.x & 63;
  const int ty = threadIdx.x >> 6;   // 0..3
  for (int i = ty; i < 64; i += 4)   // read v[bh][r0+i][tx] coalesced
    tile[i][tx] = v[((size_t)((bh << 11) + r0 + i) << 6) + tx];
  __syncthreads();
  for (int i = ty; i < 64; i += 4)   // write vT[bh][i][r0+tx] coalesced
    vT[((size_t)((bh << 6) + i) << 11) + r0 + tx] = tile[tx][i];
}

// ---------------- Kernel 1: exact bucket-rank per column --------------------
// One WG per (bh,d) column. Thread t owns idx = 4t..4t+3 and 1024+4t..+3.
// Single atomic pass: the counting atomicAdd's return value IS the
// within-bucket offset; scatter uses excl_base[b] + off (plain LDS read).
__global__ __launch_bounds__(256) void rank_kernel(
    const float* __restrict__ vT, unsigned short* __restrict__ Q,
    float* __restrict__ vs, unsigned short* __restrict__ P0) {
  const int col = blockIdx.x;        // bh*64 + d
  const int bh  = col >> 6;
  const int d   = col & 63;
  const float4* vcol4 = (const float4*)(vT + ((size_t)col << 11));

  __shared__ unsigned base[2176];                       // HS-padded 2049 (sentinel @ HS(2048)=2112)
  __shared__ unsigned long long bkt[SORT_N + 256];      // SLOT-padded scatter
  __shared__ float vsorted[SORT_N];
  __shared__ unsigned wsum[4];

  const int t = threadIdx.x;

  float x[8]; unsigned key[8]; int bk[8]; unsigned off[8];
#pragma unroll
  for (int h = 0; h < 2; ++h) {                         // 16B coalesced loads
    float4 f4 = vcol4[t + (h << 8)];
    float fv[4] = {f4.x, f4.y, f4.z, f4.w};
#pragma unroll
    for (int j = 0; j < 4; ++j) {
      const int e = (h << 2) + j;
      float f = fv[j];
      x[e] = f;
      unsigned u = __float_as_uint(f);
      key[e] = (u & 0x80000000u) ? ~u : (u | 0x80000000u);  // order-preserving
      float tb = fmaf(f, 372.3636f, 1024.0f);           // monotone bucket map
      tb = fminf(fmaxf(tb, 0.0f), 2047.0f);
      bk[e] = (int)tb;                                  // trunc==floor (tb>=0)
    }
  }
  // element e has original index IDX(e) = 4t + (e>>2)*1024 + (e&3)

  for (int i = t; i < 2176; i += 256) base[i] = 0;
  __syncthreads();

  // single atomic pass: count AND capture within-bucket offset
#pragma unroll
  for (int e = 0; e < 8; ++e) off[e] = atomicAdd(&base[HS(bk[e])], 1u);
  __syncthreads();

  // block exclusive scan over the 2048 bins (thread t owns bins 8t..8t+7)
  unsigned c[8];
#pragma unroll
  for (int e = 0; e < 8; ++e) c[e] = base[HS((t << 3) + e)];
  unsigned s = 0;
#pragma unroll
  for (int e = 0; e < 8; ++e) s += c[e];
  unsigned incl = s;
  for (int o = 1; o < 64; o <<= 1) {
    unsigned tmp = __shfl_up(incl, o);
    if ((t & 63) >= o) incl += tmp;
  }
  const int w = t >> 6;
  if ((t & 63) == 63) wsum[w] = incl;
  __syncthreads();
  unsigned run = incl - s;                              // exclusive within wave
  for (int i = 0; i < w; ++i) run += wsum[i];           // + earlier waves
#pragma unroll
  for (int e = 0; e < 8; ++e) {                         // own slots: no race
    unsigned cc = c[e];
    base[HS((t << 3) + e)] = run;                       // exclusive bucket base
    run += cc;
  }
  if (t == 0) base[HS(2048)] = SORT_N;                  // sentinel end
  __syncthreads();

  // scatter (key<<32|idx) at excl_base + captured offset (no atomics)
#pragma unroll
  for (int e = 0; e < 8; ++e) {
    unsigned idx = (unsigned)((t << 2) + ((e >> 2) << 10) + (e & 3));
    unsigned long long me = ((unsigned long long)key[e] << 32) | idx;
    bkt[SLOT(base[HS(bk[e])] + off[e])] = me;
  }
  __syncthreads();

  // exact rank = bucket start + #{strictly smaller (key,idx) in bucket}
  unsigned short* Qcol = Q + ((size_t)col << 11);
  float* vscol = vs + ((size_t)col << 11);
  unsigned short qr[8];
#pragma unroll
  for (int e = 0; e < 8; ++e) {
    unsigned idx = (unsigned)((t << 2) + ((e >> 2) << 10) + (e & 3));
    const int b = bk[e];
    unsigned start = base[HS(b)];
    unsigned end   = base[HS(b + 1)];
    unsigned long long me = ((unsigned long long)key[e] << 32) | idx;
    unsigned r = start;
    for (unsigned p = start; p < end; ++p)
      r += (bkt[SLOT(p)] < me) ? 1u : 0u;
    qr[e] = (unsigned short)r;
    vsorted[r] = x[e];                                  // LDS scatter
    if (d == 0) P0[((size_t)bh << 11) + r] = (unsigned short)idx;
  }
  {                                                     // 8B coalesced Q writes
    ushort4 qlo = {qr[0], qr[1], qr[2], qr[3]};
    ushort4 qhi = {qr[4], qr[5], qr[6], qr[7]};
    *(ushort4*)(Qcol + (t << 2)) = qlo;
    *(ushort4*)(Qcol + (t << 2) + 1024) = qhi;
  }
  __syncthreads();
  {                                                     // 16B coalesced vs write
    float4* vs4 = (float4*)vscol;
    const float4* vso4 = (const float4*)vsorted;
#pragma unroll
    for (int h = 0; h < 2; ++h) vs4[t + (h << 8)] = vso4[t + (h << 8)];
  }
}

// ------- Kernel 2a: outT[(bh,d)][r] = vs_d[Q_{d+1}[r]]  (all coalesced) -----
// d==0 blocks additionally emit spike[bh*2048+r] = P0[Q_1[r]] (they hold Q_1).
__global__ __launch_bounds__(256) void out_colT_kernel(
    const unsigned short* __restrict__ Q, const float* __restrict__ vs,
    const unsigned short* __restrict__ P0, float* __restrict__ outT,
    unsigned* __restrict__ spike) {
  const int b  = blockIdx.x;         // bh*64 + d
  const int bh = b >> 6;
  const int d  = b & 63;
  const int dn = (d + 1) & 63;
  const int t  = threadIdx.x;

  __shared__ float col[SORT_N];      // 8 KiB
  __shared__ unsigned short P0s[SORT_N];  // 4 KiB (used only by d==0 blocks)
  const float4* vcol4 = (const float4*)(vs + ((size_t)b << 11));
  float4* col4 = (float4*)col;
  for (int r4 = t; r4 < 512; r4 += 256) col4[r4] = vcol4[r4];   // 16B coalesced
  if (d == 0)
    for (int r = t; r < SORT_N; r += 256) P0s[r] = P0[((size_t)bh << 11) + r];
  __syncthreads();

  const ushort4* Qv = (const ushort4*)(Q + ((size_t)((bh << 6) + dn) << 11));
  float4* ov = (float4*)(outT + ((size_t)b << 11));
  for (int r4 = t; r4 < 512; r4 += 256) {
    ushort4 qq = Qv[r4];             // 8B coalesced ushort read
    float4 val;
    val.x = col[qq.x]; val.y = col[qq.y];
    val.z = col[qq.z]; val.w = col[qq.w];
    ov[r4] = val;                    // 16B coalesced write
    if (d == 0) {                    // spike side-product: P0[Q_1[r]]
      int r = r4 << 2;
      unsigned base_i = ((unsigned)bh << 11) + (unsigned)r;
      spike[base_i + 0] = P0s[qq.x];
      spike[base_i + 1] = P0s[qq.y];
      spike[base_i + 2] = P0s[qq.z];
      spike[base_i + 3] = P0s[qq.w];
    }
  }
}

// ------- Kernel 2b: out[r][d] = outT[d][r]  (64x64 LDS tile transpose) ------
__global__ __launch_bounds__(256) void out_transpose_kernel(
    const float* __restrict__ outT, float* __restrict__ out) {
  __shared__ float tile[64][65];     // +1 pad breaks bank conflicts
  const int blk = blockIdx.x;        // bh*32 + rtile
  const int bh = blk >> 5;
  const int r0 = (blk & 31) << 6;    // 64-row tile
  const int tx = threadIdx.x & 63;
  const int ty = threadIdx.x >> 6;   // 0..3

  for (int i = ty; i < 64; i += 4)   // read outT[d=i][r0+tx] coalesced
    tile[i][tx] = outT[(((size_t)(bh << 6) + i) << 11) + r0 + tx];
  __syncthreads();
  for (int i = ty; i < 64; i += 4)   // write out[r0+i][d=tx] coalesced
    out[(((size_t)(bh << 11) + r0 + i) << 6) + tx] = tile[tx][i];
}

// ---------------- Kernel 3: fused attn one-hot (R1-proven shape) ------------
__global__ __launch_bounds__(256) void attn_kernel(
    const unsigned* __restrict__ spike, float* __restrict__ attn) {
  const int row = blockIdx.x;        // bh*2048 + r
  const int idx = (int)spike[row];   // uniform scalar load (L2-resident 256KB)
  float4* rowp = (float4*)(attn + ((size_t)row << 11));
  const int t = threadIdx.x;
#pragma unroll
  for (int it = 0; it < 2; ++it) {
    int f4 = t + (it << 8);
    int basei = f4 << 2;
    float4 val;
    val.x = (basei + 0 == idx) ? 1.0f : 0.0f;
    val.y = (basei + 1 == idx) ? 1.0f : 0.0f;
    val.z = (basei + 2 == idx) ? 1.0f : 0.0f;
    val.w = (basei + 3 == idx) ? 1.0f : 0.0f;
    rowp[f4] = val;                  // plain store (NT measured 1.4x slower)
  }
}

extern "C" void kernel_launch(void* const* d_in, const int* in_sizes, int n_in,
                              void* d_out, int out_size, void* d_ws, size_t ws_size,
                              hipStream_t stream) {
  const float* v = (const float*)d_in[2];     // q,k unused by reference
  float* out  = (float*)d_out;
  float* attn = out + (size_t)NBH * SORT_N * NDV;
  // scratch inside the attn region (536MB); both consumed before attn_kernel:
  float* outT = attn;                                   // 16MB
  float* vT   = attn + (size_t)NBH * SORT_N * NDV;      // next 16MB

  unsigned short* Q  = (unsigned short*)d_ws;                             // 8 MiB
  float* vs          = (float*)((char*)d_ws + (size_t)8 * 1024 * 1024);   // 16 MiB
  unsigned short* P0 = (unsigned short*)((char*)d_ws + (size_t)24 * 1024 * 1024);
  unsigned* spike    = (unsigned*)((char*)d_ws + (size_t)24 * 1024 * 1024 + 256 * 1024);

  v_transpose_kernel<<<NBH * 32, 256, 0, stream>>>(v, vT);
  rank_kernel<<<NBH * NDV, 256, 0, stream>>>(vT, Q, vs, P0);
  out_colT_kernel<<<NBH * NDV, 256, 0, stream>>>(Q, vs, P0, outT, spike);
  out_transpose_kernel<<<NBH * 32, 256, 0, stream>>>(outT, out);
  attn_kernel<<<NBH * SORT_N, 256, 0, stream>>>(spike, attn);
}